// Round 9
// baseline (191.892 us; speedup 1.0000x reference)
//
#include <hip/hip_runtime.h>

// Y: 16384 x 2048 fp32 row-major. loss = sum_c |1 - (1/n) * sum_r Y[r][c]^2|
#define NROWS 16384
#define D     2048
#define D4    (D / 4)                       // 512 float4 per row
#define YBLOCKS 1024                        // row-stripe blocks (CHANGE: 512 -> 1024)
#define ROWS_PER_BLOCK (NROWS / YBLOCKS)    // 16 rows per stripe
#define K2BLK 64
// d_ws layout: P[1024][2048] floats (8 MB) | ws2[64] | counter

// Native 16B vector type (__builtin_nontemporal_load rejects HIP float4 struct).
typedef float vfloat4 __attribute__((ext_vector_type(4)));

// K1: per-column sum of squares over a 16-row stripe. grid (2,1024) x 256
// = 2048 blocks = 8 blocks/CU = 32 waves/CU (max occupancy; was 16 waves/CU).
// Thread owns 4 consecutive cols (1 float4), fully coalesced, NT loads.
__global__ void __launch_bounds__(256)
colsq_partial(const vfloat4* __restrict__ Y4, vfloat4* __restrict__ P4,
              unsigned* __restrict__ counter) {
    if (blockIdx.x == 0 && blockIdx.y == 0 && threadIdx.x == 0)
        *counter = 0u;
    const int c4 = blockIdx.x * 256 + threadIdx.x;      // [0, 512)
    const int yb = blockIdx.y;
    const vfloat4* p = Y4 + (size_t)yb * ROWS_PER_BLOCK * D4 + c4;
    vfloat4 acc = (vfloat4)(0.f);
#pragma unroll 16
    for (int r = 0; r < ROWS_PER_BLOCK; ++r) {
        vfloat4 v = __builtin_nontemporal_load(&p[(size_t)r * D4]);
        acc += v * v;
    }
    P4[(size_t)yb * D4 + c4] = acc;
}

// K2: grid 64 x 256. Block b owns cols [b*32, b*32+32); 8 threads/col,
// each sums 128 stripes. LDS-combine, |1 - s/n|, reduce 32 cols, ws2[b];
// last block (counter) sums the 64 block partials and writes out[0].
__global__ void __launch_bounds__(256)
col_finalize(const float* __restrict__ P, float* __restrict__ ws2,
             unsigned* __restrict__ counter, float* __restrict__ out) {
    const int tid  = threadIdx.x;
    const int col  = blockIdx.x * 32 + (tid & 31);
    const int part = tid >> 5;                          // 0..7
    float s = 0.f;
#pragma unroll 8
    for (int i = 0; i < YBLOCKS / 8; ++i) {             // 128 stripes/thread
        int yb = part * (YBLOCKS / 8) + i;
        s += P[(size_t)yb * D + col];
    }
    __shared__ float lds[256];
    lds[tid] = s;
    __syncthreads();
    if (tid < 32) {
        float tot = 0.f;
#pragma unroll
        for (int j = 0; j < 8; ++j)
            tot += lds[tid + 32 * j];
        float v = fabsf(1.0f - tot * (1.0f / (float)NROWS));
#pragma unroll
        for (int off = 16; off; off >>= 1)
            v += __shfl_down(v, off, 64);
        if (tid == 0) ws2[blockIdx.x] = v;
    }
    // completion counter: one agent-scope RMW per block (64 total)
    __threadfence();
    __shared__ int is_last;
    if (tid == 0) {
        unsigned old = __hip_atomic_fetch_add(counter, 1u, __ATOMIC_ACQ_REL,
                                              __HIP_MEMORY_SCOPE_AGENT);
        is_last = (old == K2BLK - 1);
    }
    __syncthreads();
    if (!is_last) return;
    if (tid < 64) {
        float v = __hip_atomic_load(&ws2[tid], __ATOMIC_RELAXED,
                                    __HIP_MEMORY_SCOPE_AGENT);
#pragma unroll
        for (int off = 32; off; off >>= 1)
            v += __shfl_down(v, off, 64);
        if (tid == 0) out[0] = v;
    }
}

extern "C" void kernel_launch(void* const* d_in, const int* in_sizes, int n_in,
                              void* d_out, int out_size, void* d_ws, size_t ws_size,
                              hipStream_t stream) {
    const vfloat4* Y4 = (const vfloat4*)d_in[0];
    float* out = (float*)d_out;
    float* P   = (float*)d_ws;                               // 8 MB partials
    float* ws2 = (float*)((char*)d_ws + (size_t)YBLOCKS * D * sizeof(float));
    unsigned* counter = (unsigned*)(ws2 + K2BLK);

    colsq_partial<<<dim3(2, YBLOCKS), 256, 0, stream>>>(Y4, (vfloat4*)P, counter);
    col_finalize<<<dim3(K2BLK), 256, 0, stream>>>(P, ws2, counter, out);
}

// Round 10
// 186.479 us; speedup vs baseline: 1.0290x; 1.0290x over previous
//
#include <hip/hip_runtime.h>

// Y: 16384 x 2048 fp32 row-major. loss = sum_c |1 - (1/n) * sum_r Y[r][c]^2|
#define NROWS 16384
#define D     2048
#define D4    (D / 4)                       // 512 float4 per row
#define YBLOCKS 512                         // row-stripe blocks (R8 geometry, best)
#define ROWS_PER_BLOCK (NROWS / YBLOCKS)    // 32 rows per stripe
#define K2BLK 64
// d_ws layout: P[512][2048] floats (4 MB) | ws2[64] | counter

typedef float vfloat4 __attribute__((ext_vector_type(4)));

// K1: per-column sum of squares over a 32-row stripe. grid (2,512) x 256.
// CHANGE vs R8: reads via inline-asm global_load_dwordx4 with `sc1 nt`
// (bypass L2, no L3 allocation) -> zero dirty-poison evictions on the read
// path. 2 batches of 16 loads, one vmcnt(0) per batch; the waitcnt asm
// takes all 16 vectors as "+v" so the FMAs cannot be scheduled above it.
__global__ void __launch_bounds__(256)
colsq_partial(const float* __restrict__ Y, vfloat4* __restrict__ P4,
              unsigned* __restrict__ counter) {
    if (blockIdx.x == 0 && blockIdx.y == 0 && threadIdx.x == 0)
        *counter = 0u;
    const int c4 = blockIdx.x * 256 + threadIdx.x;      // [0, 512)
    const int yb = blockIdx.y;
    const float* base = Y + (size_t)yb * ROWS_PER_BLOCK * D + (size_t)c4 * 4;
    vfloat4 acc = (vfloat4)(0.f);

#pragma unroll
    for (int h = 0; h < 2; ++h) {
        vfloat4 v0, v1, v2, v3, v4, v5, v6, v7,
                v8, v9, v10, v11, v12, v13, v14, v15;
#define LD(i, vr)                                                         \
        asm volatile("global_load_dwordx4 %0, %1, off sc1 nt"             \
                     : "=v"(vr)                                           \
                     : "v"(base + (size_t)(h * 16 + (i)) * D))
        LD(0, v0);   LD(1, v1);   LD(2, v2);   LD(3, v3);
        LD(4, v4);   LD(5, v5);   LD(6, v6);   LD(7, v7);
        LD(8, v8);   LD(9, v9);   LD(10, v10); LD(11, v11);
        LD(12, v12); LD(13, v13); LD(14, v14); LD(15, v15);
#undef LD
        asm volatile("s_waitcnt vmcnt(0)"
                     : "+v"(v0), "+v"(v1), "+v"(v2), "+v"(v3),
                       "+v"(v4), "+v"(v5), "+v"(v6), "+v"(v7),
                       "+v"(v8), "+v"(v9), "+v"(v10), "+v"(v11),
                       "+v"(v12), "+v"(v13), "+v"(v14), "+v"(v15)
                     :
                     : "memory");
        acc += v0 * v0;   acc += v1 * v1;   acc += v2 * v2;   acc += v3 * v3;
        acc += v4 * v4;   acc += v5 * v5;   acc += v6 * v6;   acc += v7 * v7;
        acc += v8 * v8;   acc += v9 * v9;   acc += v10 * v10; acc += v11 * v11;
        acc += v12 * v12; acc += v13 * v13; acc += v14 * v14; acc += v15 * v15;
    }
    P4[(size_t)yb * D4 + c4] = acc;
}

// K2: grid 64 x 256. Block b owns cols [b*32, b*32+32); 8 threads/col,
// each sums 64 stripes. LDS-combine, |1 - s/n|, reduce 32 cols, ws2[b];
// last block (counter) sums the 64 block partials and writes out[0].
__global__ void __launch_bounds__(256)
col_finalize(const float* __restrict__ P, float* __restrict__ ws2,
             unsigned* __restrict__ counter, float* __restrict__ out) {
    const int tid  = threadIdx.x;
    const int col  = blockIdx.x * 32 + (tid & 31);
    const int part = tid >> 5;                          // 0..7
    float s = 0.f;
#pragma unroll 8
    for (int i = 0; i < YBLOCKS / 8; ++i) {             // 64 stripes/thread
        int yb = part * (YBLOCKS / 8) + i;
        s += P[(size_t)yb * D + col];
    }
    __shared__ float lds[256];
    lds[tid] = s;
    __syncthreads();
    if (tid < 32) {
        float tot = 0.f;
#pragma unroll
        for (int j = 0; j < 8; ++j)
            tot += lds[tid + 32 * j];
        float v = fabsf(1.0f - tot * (1.0f / (float)NROWS));
#pragma unroll
        for (int off = 16; off; off >>= 1)
            v += __shfl_down(v, off, 64);
        if (tid == 0) ws2[blockIdx.x] = v;
    }
    // completion counter: one agent-scope RMW per block (64 total)
    __threadfence();
    __shared__ int is_last;
    if (tid == 0) {
        unsigned old = __hip_atomic_fetch_add(counter, 1u, __ATOMIC_ACQ_REL,
                                              __HIP_MEMORY_SCOPE_AGENT);
        is_last = (old == K2BLK - 1);
    }
    __syncthreads();
    if (!is_last) return;
    if (tid < 64) {
        float v = __hip_atomic_load(&ws2[tid], __ATOMIC_RELAXED,
                                    __HIP_MEMORY_SCOPE_AGENT);
#pragma unroll
        for (int off = 32; off; off >>= 1)
            v += __shfl_down(v, off, 64);
        if (tid == 0) out[0] = v;
    }
}

extern "C" void kernel_launch(void* const* d_in, const int* in_sizes, int n_in,
                              void* d_out, int out_size, void* d_ws, size_t ws_size,
                              hipStream_t stream) {
    const float* Y = (const float*)d_in[0];
    float* out = (float*)d_out;
    float* P   = (float*)d_ws;                               // 4 MB partials
    float* ws2 = (float*)((char*)d_ws + (size_t)YBLOCKS * D * sizeof(float));
    unsigned* counter = (unsigned*)(ws2 + K2BLK);

    colsq_partial<<<dim3(2, YBLOCKS), 256, 0, stream>>>(Y, (vfloat4*)P, counter);
    col_finalize<<<dim3(K2BLK), 256, 0, stream>>>(P, ws2, counter, out);
}